// Round 2
// baseline (2290.678 us; speedup 1.0000x reference)
//
#include <hip/hip_runtime.h>

// AdjointODE: h += dt * ( tanh(h@W1+b1) @ W2 + b2 ), 50 Euler steps.
// BATCH=32768, DIM=128, HID=256.
// Transposed-operand design: A=weights (LDS), B=state (regs). Output layout
// (lane=row, reg=dim) feeds the next matmul's B-frag via ds_bpermute quad
// shuffles -- ZERO barriers in the step loop. 256 blocks x 512 thr (8 waves,
// 2/SIMD); wave owns 16 rows; h fp32-resident in regs for all 50 steps.

typedef __attribute__((ext_vector_type(8))) short short8;
typedef __attribute__((ext_vector_type(4))) float float4v;
typedef __attribute__((ext_vector_type(4))) int int4v;

union F { int4v i; short8 s; };

#define W1S 136   // shorts per W1 row (128 k + 8 pad), 272 B (16B-aligned)
#define W2S 264   // shorts per W2 row (256 k + 8 pad), 528 B
#define W2_OFF (256 * W1S)            // 34816 shorts
#define B1_OFF (W2_OFF + 128 * W2S)   // 68608 shorts (byte 137216, 16B-aligned)
#define DT_OFF (B1_OFF + 512)         // b1f = 256 floats
#define LDS_SHORTS (DT_OFF + 128)     // 69248 shorts = 138496 B

__device__ __forceinline__ unsigned rne2(float x) {
  unsigned u = __float_as_uint(x);
  return u + 0x7fffu + ((u >> 16) & 1u);
}
// pack two fp32 -> bf16x2 dword: low short = bf16(lo), high = bf16(hi)
__device__ __forceinline__ int pack_bf16(float lo, float hi) {
  return (int)__builtin_amdgcn_perm(rne2(hi), rne2(lo), 0x07060302u);
}

// Build B-frag (4 dwords = short8) for one 32-K chunk from packed pairs of
// two 16-K tiles (tA=even, tB=odd). Dest dword jj holds k = q*8+2jj+{0,1};
// source: lane q_s = 2*(q&1)+(jj>>1) (same ln), tile = 2kc+(q>>1), pair jj&1.
__device__ __forceinline__ int4v make_frag(int addr01, int addr23, bool hiq,
                                           int a0, int a1, int b0, int b1) {
  int4v f;
  int xA, xB;
  xA = __builtin_amdgcn_ds_bpermute(addr01, a0);
  xB = __builtin_amdgcn_ds_bpermute(addr01, b0);
  f.x = hiq ? xB : xA;
  xA = __builtin_amdgcn_ds_bpermute(addr01, a1);
  xB = __builtin_amdgcn_ds_bpermute(addr01, b1);
  f.y = hiq ? xB : xA;
  xA = __builtin_amdgcn_ds_bpermute(addr23, a0);
  xB = __builtin_amdgcn_ds_bpermute(addr23, b0);
  f.z = hiq ? xB : xA;
  xA = __builtin_amdgcn_ds_bpermute(addr23, a1);
  xB = __builtin_amdgcn_ds_bpermute(addr23, b1);
  f.w = hiq ? xB : xA;
  return f;
}

extern "C" __global__ __launch_bounds__(512, 2)
void ode_kernel(const float* __restrict__ inp, const float* __restrict__ ts,
                const float* __restrict__ W1, const float* __restrict__ b1,
                const float* __restrict__ W2, const float* __restrict__ b2,
                float* __restrict__ out) {
  __shared__ __align__(16) unsigned short lds[LDS_SHORTS];
  unsigned short* w1t = lds;                  // w1t[n(hid)][k(dim)]
  unsigned short* w2t = lds + W2_OFF;         // w2t[d][k2(hid)]
  float* b1f = (float*)(lds + B1_OFF);
  float* dtf = (float*)(lds + DT_OFF);

  const int tid = threadIdx.x;
  const int wave = tid >> 6, lane = tid & 63;
  const int ln = lane & 15, q = lane >> 4;
  const int row = (blockIdx.x * 8 + wave) * 16 + ln;

  // ---- h load: T-layout, lane=row, h[t][r] = h[row][t*16+q*4+r] ----
  float4v h[8];
  #pragma unroll
  for (int t = 0; t < 8; t++)
    h[t] = *(const float4v*)&inp[row * 128 + t * 16 + q * 4];

  // ---- stage weights (bf16, transposed) + b1 + dt table ----
  for (int idx = tid; idx < 128 * 256; idx += 512) {
    int k = idx >> 8, n = idx & 255;            // W1[k][n]
    w1t[n * W1S + k] = (unsigned short)(rne2(W1[idx]) >> 16);
  }
  for (int idx = tid; idx < 256 * 128; idx += 512) {
    int k2 = idx >> 7, n2 = idx & 127;          // W2[k2][n2]
    w2t[n2 * W2S + k2] = (unsigned short)(rne2(W2[idx]) >> 16);
  }
  if (tid < 256) b1f[tid] = b1[tid];
  if (tid < 50) dtf[tid] = ts[tid + 1] - ts[tid];

  float4v b2v[8];
  #pragma unroll
  for (int t = 0; t < 8; t++)
    b2v[t] = *(const float4v*)&b2[t * 16 + q * 4];

  __syncthreads();  // the ONLY barrier

  const int addr01 = ((q & 1) * 32 + ln) * 4;  // src lane (2*(q&1))*16+ln
  const int addr23 = addr01 + 64;              // +16 lanes
  const bool hiq = q >= 2;

  #pragma unroll 1
  for (int s = 0; s < 50; s++) {
    const float dt = dtf[s];
    const float m2dt = -2.0f * dt;

    // ---- h (fp32 regs) -> bf16 B-frags, in-register shuffle ----
    int pk[8][2];
    #pragma unroll
    for (int t = 0; t < 8; t++) {
      pk[t][0] = pack_bf16(h[t][0], h[t][1]);
      pk[t][1] = pack_bf16(h[t][2], h[t][3]);
    }
    F hb[4];
    #pragma unroll
    for (int kc = 0; kc < 4; kc++)
      hb[kc].i = make_frag(addr01, addr23, hiq, pk[2 * kc][0], pk[2 * kc][1],
                           pk[2 * kc + 1][0], pk[2 * kc + 1][1]);

    #pragma unroll
    for (int c2 = 0; c2 < 4; c2++) {
      // ---- mm1: G^T tiles (m=hid, n=row), acc init = b1 ----
      float4v g[4];
      #pragma unroll
      for (int tl = 0; tl < 4; tl++)
        g[tl] = *(const float4v*)&b1f[c2 * 64 + tl * 16 + q * 4];
      #pragma unroll
      for (int tl = 0; tl < 4; tl++) {
        const unsigned short* wr = &w1t[(c2 * 64 + tl * 16 + ln) * W1S];
        #pragma unroll
        for (int kc = 0; kc < 4; kc++) {
          F w;
          w.s = *(const short8*)&wr[kc * 32 + q * 8];
          g[tl] = __builtin_amdgcn_mfma_f32_16x16x32_bf16(w.s, hb[kc].s,
                                                          g[tl], 0, 0, 0);
        }
      }
      // ---- act = dt*tanh(G) = dt - 2dt/(exp2(G*2log2e)+1), pack ----
      int pka[4][2];
      #pragma unroll
      for (int tl = 0; tl < 4; tl++) {
        float a[4];
        #pragma unroll
        for (int r = 0; r < 4; r++) {
          float e = __builtin_amdgcn_exp2f(g[tl][r] * 2.8853900817779268f);
          a[r] = fmaf(__builtin_amdgcn_rcpf(e + 1.0f), m2dt, dt);
        }
        pka[tl][0] = pack_bf16(a[0], a[1]);
        pka[tl][1] = pack_bf16(a[2], a[3]);
      }
      F ab[2];
      #pragma unroll
      for (int kc2 = 0; kc2 < 2; kc2++)
        ab[kc2].i = make_frag(addr01, addr23, hiq, pka[2 * kc2][0],
                              pka[2 * kc2][1], pka[2 * kc2 + 1][0],
                              pka[2 * kc2 + 1][1]);
      // ---- mm2: h += act @ W2 (accumulate straight into h regs) ----
      #pragma unroll
      for (int tl2 = 0; tl2 < 8; tl2++) {
        const unsigned short* wr2 = &w2t[(tl2 * 16 + ln) * W2S + c2 * 64];
        #pragma unroll
        for (int kc2 = 0; kc2 < 2; kc2++) {
          F w;
          w.s = *(const short8*)&wr2[kc2 * 32 + q * 8];
          h[tl2] = __builtin_amdgcn_mfma_f32_16x16x32_bf16(w.s, ab[kc2].s,
                                                           h[tl2], 0, 0, 0);
        }
      }
    }
    // ---- h += dt * b2 ----
    #pragma unroll
    for (int t = 0; t < 8; t++)
      #pragma unroll
      for (int r = 0; r < 4; r++) h[t][r] = fmaf(dt, b2v[t][r], h[t][r]);
  }

  // ---- store ----
  #pragma unroll
  for (int t = 0; t < 8; t++)
    *(float4v*)&out[row * 128 + t * 16 + q * 4] = h[t];
}

extern "C" void kernel_launch(void* const* d_in, const int* in_sizes, int n_in,
                              void* d_out, int out_size, void* d_ws, size_t ws_size,
                              hipStream_t stream) {
  const float* inp = (const float*)d_in[0];
  const float* ts  = (const float*)d_in[1];
  const float* W1  = (const float*)d_in[2];
  const float* b1  = (const float*)d_in[3];
  const float* W2  = (const float*)d_in[4];
  const float* b2  = (const float*)d_in[5];
  hipLaunchKernelGGL(ode_kernel, dim3(256), dim3(512), 0, stream,
                     inp, ts, W1, b1, W2, b2, (float*)d_out);
}

// Round 3
// 1180.756 us; speedup vs baseline: 1.9400x; 1.9400x over previous
//
#include <hip/hip_runtime.h>

// AdjointODE: h += dt * ( tanh(h@W1+b1) @ W2 + b2 ), 50 Euler steps.
// BATCH=32768, DIM=128, HID=256.
// 32x32x16 MFMA, A=weights (LDS), B=state (regs). 256 blocks x 256 thr
// (4 waves, 1/SIMD); wave owns 32 rows; h fp32 in regs (4 x float16 C-tiles)
// for all 50 steps. C-layout -> B-frag needs only a lane^32 exchange
// (2 ds_bpermute + selects per 16-K chunk). Biases folded into the matmuls
// as an extra K-chunk (h||1.0 @ [W1;b1], act||dt @ [W2;b2]).
// Weight LDS rows stride 76/140 dwords (== 12 mod 32): conflict-free b128.
// __launch_bounds__(256): VGPR cap 512 -- round-2's spill (5.3 GB scratch
// fetch at the 128-reg cap) cannot recur.

typedef __attribute__((ext_vector_type(8))) short short8;
typedef __attribute__((ext_vector_type(4))) float float4v;
typedef __attribute__((ext_vector_type(16))) float float16v;
typedef __attribute__((ext_vector_type(4))) int int4v;

union FB { int4v i; short8 s; };

#define W1S 152  // shorts/row: 128 dims + b1 + 15 zero-pad + 8 align-pad
#define W2S 280  // shorts/row: 256 hid + b2 + 15 zero-pad + 8 align-pad
#define W2_OFF (256 * W1S)           // 38912 shorts
#define DT_OFF (W2_OFF + 128 * W2S)  // 74752 shorts
#define LDS_SHORTS (DT_OFF + 128)    // 74880 shorts = 149760 B

__device__ __forceinline__ unsigned rne2(float x) {
  unsigned u = __float_as_uint(x);
  return u + 0x7fffu + ((u >> 16) & 1u);
}
// dword = [bf16(hi) : bf16(lo)]  (low short = lo)
__device__ __forceinline__ int pack_bf16(float lo, float hi) {
  return (int)__builtin_amdgcn_perm(rne2(hi), rne2(lo), 0x07060302u);
}

// Build one 16-K B-frag (n=lane&31, k=(lane>>5)*8+j) from 8 fp32 state regs
// r[B..B+7] in 32x32 C-layout (elem dim = (reg&3)+8*(reg>>2)+4*(lane>>5)).
// Own half supplies 4 dims, partner lane (lane^32) the other 4.
template <int B>
__device__ __forceinline__ int4v shuf16(float16v r, bool hiH, int paddr) {
  int plo0 = pack_bf16(r[B + 0], r[B + 1]);
  int plo1 = pack_bf16(r[B + 2], r[B + 3]);
  int phi0 = pack_bf16(r[B + 4], r[B + 5]);
  int phi1 = pack_bf16(r[B + 6], r[B + 7]);
  int v0 = hiH ? plo0 : phi0;  // what my partner needs from me
  int v1 = hiH ? plo1 : phi1;
  int x0 = __builtin_amdgcn_ds_bpermute(paddr, v0);
  int x1 = __builtin_amdgcn_ds_bpermute(paddr, v1);
  int4v f;
  f.x = hiH ? x0 : plo0;
  f.y = hiH ? x1 : plo1;
  f.z = hiH ? phi0 : x0;
  f.w = hiH ? phi1 : x1;
  return f;
}

#define MFMA32(a, b, c) __builtin_amdgcn_mfma_f32_32x32x16_bf16(a, b, c, 0, 0, 0)

extern "C" __global__ __launch_bounds__(256)
void ode_kernel(const float* __restrict__ inp, const float* __restrict__ ts,
                const float* __restrict__ W1, const float* __restrict__ b1,
                const float* __restrict__ W2, const float* __restrict__ b2,
                float* __restrict__ out) {
  __shared__ __align__(16) unsigned short lds[LDS_SHORTS];
  unsigned short* w1t = lds;           // w1t[n=hid][k=dim(+bias)]
  unsigned short* w2t = lds + W2_OFF;  // w2t[d=dim][k2=hid(+bias)]
  float* dtf = (float*)(lds + DT_OFF);

  const int tid = threadIdx.x;
  const int lane = tid & 63, wave = tid >> 6;
  const int ln = lane & 31;
  const bool hiH = lane >= 32;
  const int H = hiH ? 1 : 0;
  const int paddr = (lane ^ 32) << 2;
  const int row = blockIdx.x * 128 + wave * 32 + ln;

  // ---- stage W1 rows (transposed; k=128 -> b1, 129..143 -> 0) ----
  {
    const int n = tid;  // hid 0..255
    unsigned short* dst = &w1t[n * W1S];
    #pragma unroll 4
    for (int k = 0; k < 128; k++) dst[k] = (unsigned short)(rne2(W1[k * 256 + n]) >> 16);
    dst[128] = (unsigned short)(rne2(b1[n]) >> 16);
    #pragma unroll
    for (int k = 129; k < 144; k++) dst[k] = 0;
  }
  // ---- stage W2 rows (transposed; k2=256 -> b2, 257..271 -> 0) ----
  {
    const int d = tid >> 1, part = tid & 1;
    unsigned short* dst = &w2t[d * W2S];
    for (int k2 = part * 136; k2 < part * 136 + 136; k2++) {
      unsigned short v;
      if (k2 < 256) v = (unsigned short)(rne2(W2[k2 * 128 + d]) >> 16);
      else if (k2 == 256) v = (unsigned short)(rne2(b2[d]) >> 16);
      else v = 0;
      dst[k2] = v;
    }
  }
  if (tid < 50) dtf[tid] = ts[tid + 1] - ts[tid];

  // ---- load h into 32x32 C-layout: h[t][reg] = row, dim t*32+(reg&3)+8*(reg>>2)+4H ----
  float16v h[4];
  #pragma unroll
  for (int t = 0; t < 4; t++)
    #pragma unroll
    for (int g2 = 0; g2 < 4; g2++) {
      float4v v = *(const float4v*)&inp[row * 128 + t * 32 + g2 * 8 + H * 4];
      h[t][4 * g2 + 0] = v.x;
      h[t][4 * g2 + 1] = v.y;
      h[t][4 * g2 + 2] = v.z;
      h[t][4 * g2 + 3] = v.w;
    }

  __syncthreads();  // the only barrier

  #pragma unroll 1
  for (int s = 0; s < 50; s++) {
    const float dt = dtf[s];
    const float m2dt = -2.0f * dt;

    // ---- h -> 9 B-frags (8 real 16-K chunks + constant bias chunk) ----
    FB hb[9];
    #pragma unroll
    for (int t = 0; t < 4; t++) {
      hb[2 * t].i = shuf16<0>(h[t], hiH, paddr);
      hb[2 * t + 1].i = shuf16<8>(h[t], hiH, paddr);
    }
    hb[8].i = (int4v){hiH ? 0 : 0x00003F80, 0, 0, 0};  // dim128 = 1.0

    // ---- mm2 bias K-chunk: h += [dt,0..] @ [b2-row; 0..] ----
    {
      FB dfr;
      dfr.i = (int4v){hiH ? 0 : pack_bf16(dt, 0.0f), 0, 0, 0};
      #pragma unroll
      for (int mt = 0; mt < 4; mt++) {
        FB w;
        w.s = *(const short8*)&w2t[(mt * 32 + ln) * W2S + 256 + H * 8];
        h[mt] = MFMA32(w.s, dfr.s, h[mt]);
      }
    }

    // ---- 8 hid-tiles of 32: g = [h|1]@[W1;b1], act=dt*tanh(g), h += act@W2 ----
    #pragma unroll
    for (int t8 = 0; t8 < 8; t8++) {
      float16v g0 = {0.f}, g1 = {0.f};
      const unsigned short* wr = &w1t[(t8 * 32 + ln) * W1S + H * 8];
      #pragma unroll
      for (int c = 0; c < 9; c++) {
        FB w;
        w.s = *(const short8*)&wr[c * 16];
        if (c & 1) g1 = MFMA32(w.s, hb[c].s, g1);
        else       g0 = MFMA32(w.s, hb[c].s, g0);
      }
      float16v gs = g0 + g1;
      float16v a;
      #pragma unroll
      for (int r = 0; r < 16; r++) {
        float e = __builtin_amdgcn_exp2f(gs[r] * 2.8853900817779268f);
        a[r] = fmaf(__builtin_amdgcn_rcpf(e + 1.0f), m2dt, dt);  // dt*tanh
      }
      FB ab0, ab1;
      ab0.i = shuf16<0>(a, hiH, paddr);
      ab1.i = shuf16<8>(a, hiH, paddr);
      #pragma unroll
      for (int mt = 0; mt < 4; mt++) {
        const unsigned short* wr2 = &w2t[(mt * 32 + ln) * W2S + t8 * 32 + H * 8];
        FB wA, wB;
        wA.s = *(const short8*)&wr2[0];
        wB.s = *(const short8*)&wr2[16];
        h[mt] = MFMA32(wA.s, ab0.s, h[mt]);
        h[mt] = MFMA32(wB.s, ab1.s, h[mt]);
      }
    }
  }

  // ---- store ----
  #pragma unroll
  for (int t = 0; t < 4; t++)
    #pragma unroll
    for (int g2 = 0; g2 < 4; g2++) {
      float4v v = {h[t][4 * g2 + 0], h[t][4 * g2 + 1],
                   h[t][4 * g2 + 2], h[t][4 * g2 + 3]};
      *(float4v*)&out[row * 128 + t * 32 + g2 * 8 + H * 4] = v;
    }
}

extern "C" void kernel_launch(void* const* d_in, const int* in_sizes, int n_in,
                              void* d_out, int out_size, void* d_ws, size_t ws_size,
                              hipStream_t stream) {
  const float* inp = (const float*)d_in[0];
  const float* ts  = (const float*)d_in[1];
  const float* W1  = (const float*)d_in[2];
  const float* b1  = (const float*)d_in[3];
  const float* W2  = (const float*)d_in[4];
  const float* b2  = (const float*)d_in[5];
  hipLaunchKernelGGL(ode_kernel, dim3(256), dim3(256), 0, stream,
                     inp, ts, W1, b1, W2, b2, (float*)d_out);
}

// Round 4
// 428.941 us; speedup vs baseline: 5.3403x; 2.7527x over previous
//
#include <hip/hip_runtime.h>

// AdjointODE: h += dt * ( tanh(h@W1+b1) @ W2 + b2 ), 50 Euler steps.
// BATCH=32768, DIM=128, HID=256.
// 32x32x16 MFMA, A=weights (LDS), B=state (regs). 256 blocks x 256 thr
// (4 waves, 1/SIMD); wave owns 32 rows; h fp32 in regs (4 x float16 C-tiles)
// for all 50 steps. C-layout -> B-frag via lane^32 ds_bpermute exchange.
// Biases folded into the matmuls as an extra K-chunk.
// ROUND 4 FIX: t8 tile loop is `#pragma unroll 1`. Round 3's full unroll
// hoisted ~290 loop-invariant address/fragment regs past the 256-VGPR arch
// ceiling; the invariants spilled to scratch (written 64 MB once, re-read
// 1.5 GB across 50 steps -- the whole 1180us). Body register demand at
// unroll 1 is ~205 regs: fits, no scratch.

typedef __attribute__((ext_vector_type(8))) short short8;
typedef __attribute__((ext_vector_type(4))) float float4v;
typedef __attribute__((ext_vector_type(16))) float float16v;
typedef __attribute__((ext_vector_type(4))) int int4v;

union FB { int4v i; short8 s; };

#define W1S 152  // shorts/row: 128 dims + b1 + 15 zero-pad + 8 align-pad
#define W2S 280  // shorts/row: 256 hid + b2 + 15 zero-pad + 8 align-pad
#define W2_OFF (256 * W1S)           // 38912 shorts
#define DT_OFF (W2_OFF + 128 * W2S)  // 74752 shorts
#define LDS_SHORTS (DT_OFF + 128)    // 74880 shorts = 149760 B

__device__ __forceinline__ unsigned rne2(float x) {
  unsigned u = __float_as_uint(x);
  return u + 0x7fffu + ((u >> 16) & 1u);
}
// dword = [bf16(hi) : bf16(lo)]  (low short = lo)
__device__ __forceinline__ int pack_bf16(float lo, float hi) {
  return (int)__builtin_amdgcn_perm(rne2(hi), rne2(lo), 0x07060302u);
}

// Build one 16-K B-frag (n=lane&31, k=(lane>>5)*8+j) from 8 fp32 state regs
// r[B..B+7] in 32x32 C-layout (elem dim = (reg&3)+8*(reg>>2)+4*(lane>>5)).
// Own half supplies 4 dims, partner lane (lane^32) the other 4.
template <int B>
__device__ __forceinline__ int4v shuf16(float16v r, bool hiH, int paddr) {
  int plo0 = pack_bf16(r[B + 0], r[B + 1]);
  int plo1 = pack_bf16(r[B + 2], r[B + 3]);
  int phi0 = pack_bf16(r[B + 4], r[B + 5]);
  int phi1 = pack_bf16(r[B + 6], r[B + 7]);
  int v0 = hiH ? plo0 : phi0;  // what my partner needs from me
  int v1 = hiH ? plo1 : phi1;
  int x0 = __builtin_amdgcn_ds_bpermute(paddr, v0);
  int x1 = __builtin_amdgcn_ds_bpermute(paddr, v1);
  int4v f;
  f.x = hiH ? x0 : plo0;
  f.y = hiH ? x1 : plo1;
  f.z = hiH ? phi0 : x0;
  f.w = hiH ? phi1 : x1;
  return f;
}

#define MFMA32(a, b, c) __builtin_amdgcn_mfma_f32_32x32x16_bf16(a, b, c, 0, 0, 0)

extern "C" __global__ __launch_bounds__(256)
void ode_kernel(const float* __restrict__ inp, const float* __restrict__ ts,
                const float* __restrict__ W1, const float* __restrict__ b1,
                const float* __restrict__ W2, const float* __restrict__ b2,
                float* __restrict__ out) {
  __shared__ __align__(16) unsigned short lds[LDS_SHORTS];
  unsigned short* w1t = lds;           // w1t[n=hid][k=dim(+bias)]
  unsigned short* w2t = lds + W2_OFF;  // w2t[d=dim][k2=hid(+bias)]
  float* dtf = (float*)(lds + DT_OFF);

  const int tid = threadIdx.x;
  const int lane = tid & 63, wave = tid >> 6;
  const int ln = lane & 31;
  const bool hiH = lane >= 32;
  const int H = hiH ? 1 : 0;
  const int paddr = (lane ^ 32) << 2;
  const int row = blockIdx.x * 128 + wave * 32 + ln;

  // ---- stage W1 rows (transposed; k=128 -> b1, 129..143 -> 0) ----
  {
    const int n = tid;  // hid 0..255
    unsigned short* dst = &w1t[n * W1S];
    #pragma unroll 4
    for (int k = 0; k < 128; k++) dst[k] = (unsigned short)(rne2(W1[k * 256 + n]) >> 16);
    dst[128] = (unsigned short)(rne2(b1[n]) >> 16);
    #pragma unroll
    for (int k = 129; k < 144; k++) dst[k] = 0;
  }
  // ---- stage W2 rows (transposed; k2=256 -> b2, 257..271 -> 0) ----
  {
    const int d = tid >> 1, part = tid & 1;
    unsigned short* dst = &w2t[d * W2S];
    for (int k2 = part * 136; k2 < part * 136 + 136; k2++) {
      unsigned short v;
      if (k2 < 256) v = (unsigned short)(rne2(W2[k2 * 128 + d]) >> 16);
      else if (k2 == 256) v = (unsigned short)(rne2(b2[d]) >> 16);
      else v = 0;
      dst[k2] = v;
    }
  }
  if (tid < 50) dtf[tid] = ts[tid + 1] - ts[tid];

  // ---- load h into 32x32 C-layout: h[t][reg] = row, dim t*32+(reg&3)+8*(reg>>2)+4H ----
  float16v h[4];
  #pragma unroll
  for (int t = 0; t < 4; t++)
    #pragma unroll
    for (int g2 = 0; g2 < 4; g2++) {
      float4v v = *(const float4v*)&inp[row * 128 + t * 32 + g2 * 8 + H * 4];
      h[t][4 * g2 + 0] = v.x;
      h[t][4 * g2 + 1] = v.y;
      h[t][4 * g2 + 2] = v.z;
      h[t][4 * g2 + 3] = v.w;
    }

  __syncthreads();  // the only barrier

  #pragma unroll 1
  for (int s = 0; s < 50; s++) {
    const float dt = dtf[s];
    const float m2dt = -2.0f * dt;

    // ---- h -> 9 B-frags (8 real 16-K chunks + constant bias chunk) ----
    FB hb[9];
    #pragma unroll
    for (int t = 0; t < 4; t++) {
      hb[2 * t].i = shuf16<0>(h[t], hiH, paddr);
      hb[2 * t + 1].i = shuf16<8>(h[t], hiH, paddr);
    }
    hb[8].i = (int4v){hiH ? 0 : 0x00003F80, 0, 0, 0};  // dim128 = 1.0

    // ---- mm2 bias K-chunk: h += [dt,0..] @ [b2-row; 0..] ----
    {
      FB dfr;
      dfr.i = (int4v){hiH ? 0 : pack_bf16(dt, 0.0f), 0, 0, 0};
      #pragma unroll
      for (int mt = 0; mt < 4; mt++) {
        FB w;
        w.s = *(const short8*)&w2t[(mt * 32 + ln) * W2S + 256 + H * 8];
        h[mt] = MFMA32(w.s, dfr.s, h[mt]);
      }
    }

    // ---- 8 hid-tiles of 32: g = [h|1]@[W1;b1], act=dt*tanh(g), h += act@W2 ----
    // unroll 1: keeps live range ~205 regs (< 256 arch VGPRs, no scratch).
    #pragma unroll 1
    for (int t8 = 0; t8 < 8; t8++) {
      float16v g0 = {0.f}, g1 = {0.f};
      const unsigned short* wr = &w1t[(t8 * 32 + ln) * W1S + H * 8];
      #pragma unroll
      for (int c = 0; c < 9; c++) {
        FB w;
        w.s = *(const short8*)&wr[c * 16];
        if (c & 1) g1 = MFMA32(w.s, hb[c].s, g1);
        else       g0 = MFMA32(w.s, hb[c].s, g0);
      }
      float16v gs = g0 + g1;
      float16v a;
      #pragma unroll
      for (int r = 0; r < 16; r++) {
        float e = __builtin_amdgcn_exp2f(gs[r] * 2.8853900817779268f);
        a[r] = fmaf(__builtin_amdgcn_rcpf(e + 1.0f), m2dt, dt);  // dt*tanh
      }
      FB ab0, ab1;
      ab0.i = shuf16<0>(a, hiH, paddr);
      ab1.i = shuf16<8>(a, hiH, paddr);
      #pragma unroll
      for (int mt = 0; mt < 4; mt++) {
        const unsigned short* wr2 = &w2t[(mt * 32 + ln) * W2S + t8 * 32 + H * 8];
        FB wA, wB;
        wA.s = *(const short8*)&wr2[0];
        wB.s = *(const short8*)&wr2[16];
        h[mt] = MFMA32(wA.s, ab0.s, h[mt]);
        h[mt] = MFMA32(wB.s, ab1.s, h[mt]);
      }
    }
  }

  // ---- store ----
  #pragma unroll
  for (int t = 0; t < 4; t++)
    #pragma unroll
    for (int g2 = 0; g2 < 4; g2++) {
      float4v v = {h[t][4 * g2 + 0], h[t][4 * g2 + 1],
                   h[t][4 * g2 + 2], h[t][4 * g2 + 3]};
      *(float4v*)&out[row * 128 + t * 32 + g2 * 8 + H * 4] = v;
    }
}

extern "C" void kernel_launch(void* const* d_in, const int* in_sizes, int n_in,
                              void* d_out, int out_size, void* d_ws, size_t ws_size,
                              hipStream_t stream) {
  const float* inp = (const float*)d_in[0];
  const float* ts  = (const float*)d_in[1];
  const float* W1  = (const float*)d_in[2];
  const float* b1  = (const float*)d_in[3];
  const float* W2  = (const float*)d_in[4];
  const float* b2  = (const float*)d_in[5];
  hipLaunchKernelGGL(ode_kernel, dim3(256), dim3(256), 0, stream,
                     inp, ts, W1, b1, W2, b2, (float*)d_out);
}

// Round 5
// 398.741 us; speedup vs baseline: 5.7448x; 1.0757x over previous
//
#include <hip/hip_runtime.h>

// AdjointODE: h += dt * ( tanh(h@W1+b1) @ W2 + b2 ), 50 Euler steps.
// BATCH=32768, DIM=128, HID=256.
// 32x32x16 MFMA, A=weights (LDS), B=state (regs). 256 blocks x 256 thr
// (4 waves, 1/SIMD); wave owns 32 rows; h fp32 in regs (4 x float16 C-tiles).
// ROUND 5: K-SWIZZLED weight layout. Within each 16-wide K-chunk, the LDS
// weight rows are stored with middle quads swapped (o: [4-7]<->[8-11]) so the
// MFMA's logical K order matches the C-layout register order of the state.
// B-frags are then built by packing CONSECUTIVE register pairs -- the entire
// ds_bpermute + cndmask shuffle network from rounds 2-4 is gone. A-frag reads
// stay single ds_read_b128 at identical (conflict-free) addresses.
// Also: v_cvt_pk_bf16_f32 packing when available; W2 frag loads hoisted under
// the tanh transcendental stretch. t8 loop stays unroll 1 (round-3 lesson:
// full unroll -> 256-VGPR spill disaster).

typedef __attribute__((ext_vector_type(8))) short short8;
typedef __attribute__((ext_vector_type(4))) float float4v;
typedef __attribute__((ext_vector_type(16))) float float16v;
typedef __attribute__((ext_vector_type(4))) int int4v;

union FB { int4v i; short8 s; };

#define W1S 152  // shorts/row: 128 dims + b1 + 15 zero-pad + 8 align-pad
#define W2S 280  // shorts/row: 256 hid + b2 + 15 zero-pad + 8 align-pad
#define W2_OFF (256 * W1S)           // 38912 shorts
#define DT_OFF (W2_OFF + 128 * W2S)  // 74752 shorts
#define LDS_SHORTS (DT_OFF + 128)    // 74880 shorts = 149760 B

__device__ __forceinline__ unsigned rne2(float x) {
  unsigned u = __float_as_uint(x);
  return u + 0x7fffu + ((u >> 16) & 1u);
}

#if __has_builtin(__builtin_amdgcn_cvt_pk_bf16_f32)
__device__ __forceinline__ int pk2(float lo, float hi) {
  return __builtin_bit_cast(int, __builtin_amdgcn_cvt_pk_bf16_f32(lo, hi));
}
#else
// fallback: manual RNE pack (proven rounds 1-4)
__device__ __forceinline__ int pk2(float lo, float hi) {
  return (int)__builtin_amdgcn_perm(rne2(hi), rne2(lo), 0x07060302u);
}
#endif

// K-swizzle: within each 16-block swap quads [4-7] <-> [8-11] (involution).
// Storage position of logical dim k. Makes MFMA logical-K order == C-layout
// register order for the state operand.
__device__ __forceinline__ int swzk(int k) {
  return (k & ~15) | (k & 3) | ((k & 4) << 1) | ((k & 8) >> 1);
}

// B-frag for one 16-K chunk = pack 8 consecutive C-layout regs (base B8).
template <int B8>
__device__ __forceinline__ int4v packfrag(float16v r) {
  int4v f;
  f.x = pk2(r[B8 + 0], r[B8 + 1]);
  f.y = pk2(r[B8 + 2], r[B8 + 3]);
  f.z = pk2(r[B8 + 4], r[B8 + 5]);
  f.w = pk2(r[B8 + 6], r[B8 + 7]);
  return f;
}

#define MFMA32(a, b, c) __builtin_amdgcn_mfma_f32_32x32x16_bf16(a, b, c, 0, 0, 0)

extern "C" __global__ __launch_bounds__(256)
void ode_kernel(const float* __restrict__ inp, const float* __restrict__ ts,
                const float* __restrict__ W1, const float* __restrict__ b1,
                const float* __restrict__ W2, const float* __restrict__ b2,
                float* __restrict__ out) {
  __shared__ __align__(16) unsigned short lds[LDS_SHORTS];
  unsigned short* w1t = lds;           // w1t[n=hid][swzk(k=dim,+bias)]
  unsigned short* w2t = lds + W2_OFF;  // w2t[d=dim][swzk(k2=hid,+bias)]
  float* dtf = (float*)(lds + DT_OFF);

  const int tid = threadIdx.x;
  const int lane = tid & 63, wave = tid >> 6;
  const int ln = lane & 31;
  const int H = lane >> 5;  // A/B K-group half
  const int row = blockIdx.x * 128 + wave * 32 + ln;

  // ---- stage W1 rows (transposed + K-swizzled; k=128 -> b1, pads 0) ----
  {
    const int n = tid;  // hid 0..255
    unsigned short* dst = &w1t[n * W1S];
    #pragma unroll 4
    for (int k = 0; k < 128; k++)
      dst[swzk(k)] = (unsigned short)(rne2(W1[k * 256 + n]) >> 16);
    dst[128] = (unsigned short)(rne2(b1[n]) >> 16);  // swzk(128)==128
    #pragma unroll
    for (int k = 129; k < 144; k++) dst[swzk(k)] = 0;
  }
  // ---- stage W2 rows (transposed + K-swizzled; k2=256 -> b2, pads 0) ----
  {
    const int d = tid >> 1, part = tid & 1;
    unsigned short* dst = &w2t[d * W2S];
    for (int k2 = part * 136; k2 < part * 136 + 136; k2++) {
      unsigned short v;
      if (k2 < 256) v = (unsigned short)(rne2(W2[k2 * 128 + d]) >> 16);
      else if (k2 == 256) v = (unsigned short)(rne2(b2[d]) >> 16);
      else v = 0;
      dst[swzk(k2)] = v;
    }
  }
  if (tid < 50) dtf[tid] = ts[tid + 1] - ts[tid];

  // ---- load h into 32x32 C-layout: h[t][reg] = row, dim t*32+(reg&3)+8*(reg>>2)+4H ----
  float16v h[4];
  #pragma unroll
  for (int t = 0; t < 4; t++)
    #pragma unroll
    for (int g2 = 0; g2 < 4; g2++) {
      float4v v = *(const float4v*)&inp[row * 128 + t * 32 + g2 * 8 + H * 4];
      h[t][4 * g2 + 0] = v.x;
      h[t][4 * g2 + 1] = v.y;
      h[t][4 * g2 + 2] = v.z;
      h[t][4 * g2 + 3] = v.w;
    }

  __syncthreads();  // the only barrier

  #pragma unroll 1
  for (int s = 0; s < 50; s++) {
    const float dt = dtf[s];
    const float m2dt = -2.0f * dt;

    // ---- h -> 9 B-frags: pure register packing (no cross-lane ops) ----
    FB hb[9];
    #pragma unroll
    for (int t = 0; t < 4; t++) {
      hb[2 * t].i = packfrag<0>(h[t]);
      hb[2 * t + 1].i = packfrag<8>(h[t]);
    }
    hb[8].i = (int4v){H ? 0 : 0x00003F80, 0, 0, 0};  // dim128 = 1.0

    // ---- mm2 bias K-chunk: h += [dt,0..] @ [b2-row; 0..] ----
    {
      FB dfr;
      dfr.i = (int4v){H ? 0 : pk2(dt, 0.0f), 0, 0, 0};
      #pragma unroll
      for (int mt = 0; mt < 4; mt++) {
        FB w;
        w.s = *(const short8*)&w2t[(mt * 32 + ln) * W2S + 256 + H * 8];
        h[mt] = MFMA32(w.s, dfr.s, h[mt]);
      }
    }

    // ---- 8 hid-tiles: g = [h|1]@[W1;b1], act=dt*tanh(g), h += act@W2 ----
    #pragma unroll 1
    for (int t8 = 0; t8 < 8; t8++) {
      // W1 frag reads up front (queued b128s stream into the MFMA chain)
      FB w1f[9];
      const unsigned short* wr = &w1t[(t8 * 32 + ln) * W1S + H * 8];
      #pragma unroll
      for (int c = 0; c < 9; c++) w1f[c].s = *(const short8*)&wr[c * 16];

      float16v g0 = {0.f}, g1 = {0.f};
      #pragma unroll
      for (int c = 0; c < 9; c++) {
        if (c & 1) g1 = MFMA32(w1f[c].s, hb[c].s, g1);
        else       g0 = MFMA32(w1f[c].s, hb[c].s, g0);
      }
      float16v gs = g0 + g1;

      // W2 frag loads issued BEFORE tanh: transcendental stretch hides LDS latency
      FB w2f[8];
      #pragma unroll
      for (int mt = 0; mt < 4; mt++) {
        const unsigned short* wr2 = &w2t[(mt * 32 + ln) * W2S + t8 * 32 + H * 8];
        w2f[2 * mt].s     = *(const short8*)&wr2[0];
        w2f[2 * mt + 1].s = *(const short8*)&wr2[16];
      }

      float16v a;
      #pragma unroll
      for (int r = 0; r < 16; r++) {
        float e = __builtin_amdgcn_exp2f(gs[r] * 2.8853900817779268f);
        a[r] = fmaf(__builtin_amdgcn_rcpf(e + 1.0f), m2dt, dt);  // dt*tanh
      }
      FB ab0, ab1;
      ab0.i = packfrag<0>(a);
      ab1.i = packfrag<8>(a);

      #pragma unroll
      for (int mt = 0; mt < 4; mt++) {
        h[mt] = MFMA32(w2f[2 * mt].s, ab0.s, h[mt]);
        h[mt] = MFMA32(w2f[2 * mt + 1].s, ab1.s, h[mt]);
      }
    }
  }

  // ---- store ----
  #pragma unroll
  for (int t = 0; t < 4; t++)
    #pragma unroll
    for (int g2 = 0; g2 < 4; g2++) {
      float4v v = {h[t][4 * g2 + 0], h[t][4 * g2 + 1],
                   h[t][4 * g2 + 2], h[t][4 * g2 + 3]};
      *(float4v*)&out[row * 128 + t * 32 + g2 * 8 + H * 4] = v;
    }
}

extern "C" void kernel_launch(void* const* d_in, const int* in_sizes, int n_in,
                              void* d_out, int out_size, void* d_ws, size_t ws_size,
                              hipStream_t stream) {
  const float* inp = (const float*)d_in[0];
  const float* ts  = (const float*)d_in[1];
  const float* W1  = (const float*)d_in[2];
  const float* b1  = (const float*)d_in[3];
  const float* W2  = (const float*)d_in[4];
  const float* b2  = (const float*)d_in[5];
  hipLaunchKernelGGL(ode_kernel, dim3(256), dim3(256), 0, stream,
                     inp, ts, W1, b1, W2, b2, (float*)d_out);
}

// Round 6
// 386.099 us; speedup vs baseline: 5.9329x; 1.0327x over previous
//
#include <hip/hip_runtime.h>

// AdjointODE: h += dt * ( tanh(h@W1+b1) @ W2 + b2 ), 50 Euler steps.
// BATCH=32768, DIM=128, HID=256.
// 32x32x16 MFMA, A=weights (LDS, K-swizzled), B=state (regs, C-layout packed
// in-place -- no cross-lane shuffles). 256 blocks x 256 thr (4 waves, 1/SIMD
// grid-fixed); wave owns 32 rows; h fp32-resident (4 x float16 C-tiles).
// ROUND 6: SKEWED SOFTWARE PIPELINE over hid-tiles. mm1(t+1) (9 MFMAs + LDS
// reads, depends only on step-start hb) is computed in the same loop body as
// tanh(t)+mm2(t), so the scheduler hides the mm1 dep-chain under the
// transcendental stretch and vice versa. Single-g accumulator (chain latency
// now hidden; saves 16 adds + 32 regs). Outer loops unroll-1 (round-3 lesson:
// full unroll -> 256-VGPR spill disaster; canary = FETCH_SIZE ~9.3 MB).

typedef __attribute__((ext_vector_type(8))) short short8;
typedef __attribute__((ext_vector_type(4))) float float4v;
typedef __attribute__((ext_vector_type(16))) float float16v;
typedef __attribute__((ext_vector_type(4))) int int4v;

union FB { int4v i; short8 s; };

#define W1S 152  // shorts/row: 128 dims + b1 + 15 zero-pad + 8 align-pad
#define W2S 280  // shorts/row: 256 hid + b2 + 15 zero-pad + 8 align-pad
#define W2_OFF (256 * W1S)           // 38912 shorts
#define DT_OFF (W2_OFF + 128 * W2S)  // 74752 shorts
#define LDS_SHORTS (DT_OFF + 128)    // 74880 shorts = 149760 B

__device__ __forceinline__ unsigned rne2(float x) {
  unsigned u = __float_as_uint(x);
  return u + 0x7fffu + ((u >> 16) & 1u);
}

#if __has_builtin(__builtin_amdgcn_cvt_pk_bf16_f32)
__device__ __forceinline__ int pk2(float lo, float hi) {
  return __builtin_bit_cast(int, __builtin_amdgcn_cvt_pk_bf16_f32(lo, hi));
}
#else
__device__ __forceinline__ int pk2(float lo, float hi) {
  return (int)__builtin_amdgcn_perm(rne2(hi), rne2(lo), 0x07060302u);
}
#endif

// K-swizzle: within each 16-block swap quads [4-7] <-> [8-11] (involution).
// Makes MFMA logical-K order == C-layout register order of the state operand.
__device__ __forceinline__ int swzk(int k) {
  return (k & ~15) | (k & 3) | ((k & 4) << 1) | ((k & 8) >> 1);
}

// B-frag for one 16-K chunk = pack 8 consecutive C-layout regs (base B8).
template <int B8>
__device__ __forceinline__ int4v packfrag(float16v r) {
  int4v f;
  f.x = pk2(r[B8 + 0], r[B8 + 1]);
  f.y = pk2(r[B8 + 2], r[B8 + 3]);
  f.z = pk2(r[B8 + 4], r[B8 + 5]);
  f.w = pk2(r[B8 + 6], r[B8 + 7]);
  return f;
}

#define MFMA32(a, b, c) __builtin_amdgcn_mfma_f32_32x32x16_bf16(a, b, c, 0, 0, 0)

// tanh + pack + mm2 for one finished hid-tile (the "tail" stage of the pipe).
__device__ __forceinline__ void tile_tail(float16v g, float dt, float m2dt,
                                          int t8, const unsigned short* w2t,
                                          int ln, int H, float16v h[4]) {
  float16v a;
  #pragma unroll
  for (int r = 0; r < 16; r++) {
    float e = __builtin_amdgcn_exp2f(g[r] * 2.8853900817779268f);
    a[r] = fmaf(__builtin_amdgcn_rcpf(e + 1.0f), m2dt, dt);  // dt*tanh(g)
  }
  FB ab0, ab1;
  ab0.i = packfrag<0>(a);
  ab1.i = packfrag<8>(a);
  #pragma unroll
  for (int mt = 0; mt < 4; mt++) {
    const unsigned short* wr2 = &w2t[(mt * 32 + ln) * W2S + t8 * 32 + H * 8];
    FB wA, wB;
    wA.s = *(const short8*)&wr2[0];
    wB.s = *(const short8*)&wr2[16];
    h[mt] = MFMA32(wA.s, ab0.s, h[mt]);
    h[mt] = MFMA32(wB.s, ab1.s, h[mt]);
  }
}

extern "C" __global__ __launch_bounds__(256)
void ode_kernel(const float* __restrict__ inp, const float* __restrict__ ts,
                const float* __restrict__ W1, const float* __restrict__ b1,
                const float* __restrict__ W2, const float* __restrict__ b2,
                float* __restrict__ out) {
  __shared__ __align__(16) unsigned short lds[LDS_SHORTS];
  unsigned short* w1t = lds;           // w1t[n=hid][swzk(k=dim,+bias)]
  unsigned short* w2t = lds + W2_OFF;  // w2t[d=dim][swzk(k2=hid,+bias)]
  float* dtf = (float*)(lds + DT_OFF);

  const int tid = threadIdx.x;
  const int lane = tid & 63, wave = tid >> 6;
  const int ln = lane & 31;
  const int H = lane >> 5;  // K-group half
  const int row = blockIdx.x * 128 + wave * 32 + ln;

  // ---- stage W1 rows (transposed + K-swizzled; k=128 -> b1, pads 0) ----
  {
    const int n = tid;  // hid 0..255
    unsigned short* dst = &w1t[n * W1S];
    #pragma unroll 4
    for (int k = 0; k < 128; k++)
      dst[swzk(k)] = (unsigned short)(rne2(W1[k * 256 + n]) >> 16);
    dst[128] = (unsigned short)(rne2(b1[n]) >> 16);  // swzk(128)==128
    #pragma unroll
    for (int k = 129; k < 144; k++) dst[swzk(k)] = 0;
  }
  // ---- stage W2 rows (transposed + K-swizzled; k2=256 -> b2, pads 0) ----
  {
    const int d = tid >> 1, part = tid & 1;
    unsigned short* dst = &w2t[d * W2S];
    for (int k2 = part * 136; k2 < part * 136 + 136; k2++) {
      unsigned short v;
      if (k2 < 256) v = (unsigned short)(rne2(W2[k2 * 128 + d]) >> 16);
      else if (k2 == 256) v = (unsigned short)(rne2(b2[d]) >> 16);
      else v = 0;
      dst[swzk(k2)] = v;
    }
  }
  if (tid < 50) dtf[tid] = ts[tid + 1] - ts[tid];

  // ---- load h into 32x32 C-layout: h[t][reg] = row, dim t*32+(reg&3)+8*(reg>>2)+4H ----
  float16v h[4];
  #pragma unroll
  for (int t = 0; t < 4; t++)
    #pragma unroll
    for (int g2 = 0; g2 < 4; g2++) {
      float4v v = *(const float4v*)&inp[row * 128 + t * 32 + g2 * 8 + H * 4];
      h[t][4 * g2 + 0] = v.x;
      h[t][4 * g2 + 1] = v.y;
      h[t][4 * g2 + 2] = v.z;
      h[t][4 * g2 + 3] = v.w;
    }

  __syncthreads();  // the only barrier

  #pragma unroll 1
  for (int s = 0; s < 50; s++) {
    const float dt = dtf[s];
    const float m2dt = -2.0f * dt;

    // ---- h -> 9 B-frags: pure register packing (no cross-lane ops) ----
    FB hb[9];
    #pragma unroll
    for (int t = 0; t < 4; t++) {
      hb[2 * t].i = packfrag<0>(h[t]);
      hb[2 * t + 1].i = packfrag<8>(h[t]);
    }
    hb[8].i = (int4v){H ? 0 : 0x00003F80, 0, 0, 0};  // dim128 = 1.0

    // ---- mm2 bias K-chunk: h += [dt,0..] @ [b2-row; 0..] (overlaps prologue) ----
    {
      FB dfr;
      dfr.i = (int4v){H ? 0 : pk2(dt, 0.0f), 0, 0, 0};
      #pragma unroll
      for (int mt = 0; mt < 4; mt++) {
        FB w;
        w.s = *(const short8*)&w2t[(mt * 32 + ln) * W2S + 256 + H * 8];
        h[mt] = MFMA32(w.s, dfr.s, h[mt]);
      }
    }

    // ---- prologue: g = mm1(tile 0) ----
    float16v g = {0.f};
    {
      const unsigned short* wr = &w1t[ln * W1S + H * 8];
      #pragma unroll
      for (int c = 0; c < 9; c++) {
        FB w;
        w.s = *(const short8*)&wr[c * 16];
        g = MFMA32(w.s, hb[c].s, g);
      }
    }

    // ---- pipelined tiles: body t computes mm1(t+1) AND tail(t) ----
    #pragma unroll 1
    for (int t8 = 0; t8 < 7; t8++) {
      float16v gn = {0.f};
      const unsigned short* wr = &w1t[((t8 + 1) * 32 + ln) * W1S + H * 8];
      #pragma unroll
      for (int c = 0; c < 9; c++) {
        FB w;
        w.s = *(const short8*)&wr[c * 16];
        gn = MFMA32(w.s, hb[c].s, gn);
      }
      tile_tail(g, dt, m2dt, t8, w2t, ln, H, h);
      g = gn;
    }
    tile_tail(g, dt, m2dt, 7, w2t, ln, H, h);  // epilogue tile
  }

  // ---- store ----
  #pragma unroll
  for (int t = 0; t < 4; t++)
    #pragma unroll
    for (int g2 = 0; g2 < 4; g2++) {
      float4v v = {h[t][4 * g2 + 0], h[t][4 * g2 + 1],
                   h[t][4 * g2 + 2], h[t][4 * g2 + 3]};
      *(float4v*)&out[row * 128 + t * 32 + g2 * 8 + H * 4] = v;
    }
}

extern "C" void kernel_launch(void* const* d_in, const int* in_sizes, int n_in,
                              void* d_out, int out_size, void* d_ws, size_t ws_size,
                              hipStream_t stream) {
  const float* inp = (const float*)d_in[0];
  const float* ts  = (const float*)d_in[1];
  const float* W1  = (const float*)d_in[2];
  const float* b1  = (const float*)d_in[3];
  const float* W2  = (const float*)d_in[4];
  const float* b2  = (const float*)d_in[5];
  hipLaunchKernelGGL(ode_kernel, dim3(256), dim3(256), 0, stream,
                     inp, ts, W1, b1, W2, b2, (float*)d_out);
}